// Round 20
// baseline (427.029 us; speedup 1.0000x reference)
//
#include <hip/hip_runtime.h>

#define N_NODES 1048576
#define N_SEG   16384
#define NPS     64
#define D       128
#define EPS     1e-5f

typedef float f4 __attribute__((ext_vector_type(4)));
typedef float f32x4 __attribute__((ext_vector_type(4)));
typedef __bf16 bf16x8 __attribute__((ext_vector_type(8)));

// ---------- K1: column sum / sumsq partials (deterministic, no atomics) ----------
__global__ __launch_bounds__(256) void k_stats(const float* __restrict__ feat,
                                               float* __restrict__ part) {
    int t = threadIdx.x;
    long gid = (long)blockIdx.x * 256 + t;       // float4 index
    const f4* f4p = (const f4*)feat;
    f4 s = {0.f,0.f,0.f,0.f}, q = {0.f,0.f,0.f,0.f};
#pragma unroll 8
    for (int k = 0; k < 64; ++k) {
        f4 v = f4p[gid + (long)k * 524288];      // stride = 2048*256 float4s
        s += v;
        q += v * v;
    }
    __shared__ f4 red[2][8][32];
    red[0][t >> 5][t & 31] = s;
    red[1][t >> 5][t & 31] = q;
    __syncthreads();
    int stat = t >> 7, c = t & 127;
    const float* base = (const float*)&red[stat][0][0];
    float acc = 0.f;
#pragma unroll
    for (int r = 0; r < 8; ++r) acc += base[r * 128 + c];
    part[(stat * 128 + c) * 2048 + blockIdx.x] = acc;
}

// ---------- K1b: reduce partials -> scale/shift ----------
__global__ __launch_bounds__(256) void k_scale(const float* __restrict__ part,
                                               const float* __restrict__ gamma,
                                               const float* __restrict__ beta,
                                               float* __restrict__ scl,
                                               float* __restrict__ shf) {
    int t = threadIdx.x, c = blockIdx.x;
    float s1 = 0.f, s2 = 0.f;
#pragma unroll
    for (int j = 0; j < 8; ++j) {
        s1 += part[c * 2048 + t + 256 * j];
        s2 += part[(128 + c) * 2048 + t + 256 * j];
    }
    __shared__ float rs[256], rq[256];
    rs[t] = s1; rq[t] = s2;
    __syncthreads();
    for (int off = 128; off > 0; off >>= 1) {
        if (t < off) { rs[t] += rs[t + off]; rq[t] += rq[t + off]; }
        __syncthreads();
    }
    if (t == 0) {
        float mean = rs[0] / (float)N_NODES;
        float var  = rq[0] / (float)N_NODES - mean * mean;
        float sc   = gamma[c] * rsqrtf(var + EPS);
        scl[c] = sc;
        shf[c] = beta[c] - mean * sc;
    }
}

// ---------- K1c: cu[h] = sum_d shf[d]*Wu[h][d]  (tiny) ----------
__global__ __launch_bounds__(128) void k_const(const float* __restrict__ Wu,
                                               const float* __restrict__ shf,
                                               float* __restrict__ cu) {
    int h = threadIdx.x;
    float acc = 0.f;
#pragma unroll 8
    for (int d = 0; d < 128; ++d) acc += shf[d] * Wu[h * 128 + d];
    cu[h] = acc;
}

// ---------- K2a: flp'[seg][h] = f_last_norm @ Wi^T + bi + cu  (R2-proven shape) ----
__global__ __launch_bounds__(256) void k_flp(const float* __restrict__ feat,
                                             const float* __restrict__ Wi,
                                             const float* __restrict__ bi,
                                             const float* __restrict__ scl,
                                             const float* __restrict__ shf,
                                             const float* __restrict__ cu,
                                             float* __restrict__ flp) {
    __shared__ float sWiT[128][129];   // sWiT[d][h] = Wi[h][d]
    __shared__ float fl[2][128];
    int t = threadIdx.x;
    for (int i = t; i < 16384; i += 256) sWiT[i & 127][i >> 7] = Wi[i];
    int half = t >> 7, c = t & 127;
    float add = bi[c] + cu[c];
    float sc = scl[c], sh = shf[c];
    __syncthreads();
    for (int s = 0; s < 16; ++s) {
        int seg = blockIdx.x * 32 + 2 * s + half;
        long row = (long)seg * NPS + (NPS - 1);
        fl[half][c] = feat[row * 128 + c] * sc + sh;
        __syncthreads();
        float acc = add;
#pragma unroll
        for (int d = 0; d < 128; ++d) acc += fl[half][d] * sWiT[d][c];
        flp[seg * 128 + c] = acc;
        __syncthreads();
    }
}

// ---------- helpers ----------
__device__ inline unsigned pk2(float x, float y) {   // pack 2 floats -> 2 bf16 (RNE)
    unsigned a = __builtin_bit_cast(unsigned, x);
    unsigned b = __builtin_bit_cast(unsigned, y);
    a = (a + 0x7fffu + ((a >> 16) & 1u)) >> 16;
    b = (b + 0x7fffu + ((b >> 16) & 1u)) & 0xffff0000u;
    return a | b;
}
__device__ inline bf16x8 lds8(const unsigned short* p, int row, int kb) {
    int addr = (row * 256 + kb) ^ ((row & 7) << 4);  // T2 XOR swizzle (bf16 tile)
    return *(const bf16x8*)((const char*)p + addr);
}

// ---------- K2b: gate kernel — e[n] only. Wave-autonomous, zero main barriers ----
// sW = Wu*diag(scl) (BN folded); af packs RAW feat; flp' carries bi+cu.
// Macros verbatim from R18 (compiled+refcheck'd), minus the scl/shf in PACKC.
__global__ __launch_bounds__(256)
void k_e(const float* __restrict__ feat,
         const float* __restrict__ Wu,
         const float* __restrict__ we,
         const float* __restrict__ scl,
         const float* __restrict__ flp,
         float* __restrict__ e_out) {
    __shared__ __align__(16) unsigned short sW[128 * 128];   // 32KB Wu' bf16 swizzled
    __shared__ float flp_s[8][128];                          // 4KB
    __shared__ float we_s[128];

    int t = threadIdx.x;
    int lane = t & 63, w = t >> 6;
    int l15 = lane & 15, g4 = lane >> 4;
    int seg0 = blockIdx.x * 8;

    if (t < 128) we_s[t] = we[t];
    {   // stage sW = Wu * diag(scl), bf16 swizzled
        const f4* W4 = (const f4*)Wu;
#pragma unroll
        for (int k = 0; k < 16; ++k) {
            int g = t + 256 * k, h = g >> 5, cq = g & 31;
            f4 v = W4[g] * (*(const f4*)(scl + 4 * cq));
            int addr = (h * 256 + cq * 8) ^ ((h & 7) << 4);
            *(uint2*)((char*)sW + addr) = make_uint2(pk2(v.x, v.y), pk2(v.z, v.w));
        }
    }
#pragma unroll
    for (int j = 0; j < 4; ++j) {
        int idx = t + 256 * j;
        flp_s[idx >> 7][idx & 127] = flp[seg0 * 128 + idx];
    }
    __syncthreads();

#define LOADC(RAW, C)                                                       \
    do {                                                                    \
        const float* p_ = fb + (16 * (C) + l15) * 128 + g4 * 8;             \
        RAW[0] = *(const f4*)(p_);       RAW[1] = *(const f4*)(p_ + 4);     \
        RAW[2] = *(const f4*)(p_ + 32);  RAW[3] = *(const f4*)(p_ + 36);    \
        RAW[4] = *(const f4*)(p_ + 64);  RAW[5] = *(const f4*)(p_ + 68);    \
        RAW[6] = *(const f4*)(p_ + 96);  RAW[7] = *(const f4*)(p_ + 100);   \
    } while (0)
#define PACKC(RAW, AF)                                                      \
    do {                                                                    \
        _Pragma("unroll")                                                   \
        for (int kk = 0; kk < 4; ++kk) {                                    \
            f4 u = RAW[2 * kk];                                             \
            f4 v = RAW[2 * kk + 1];                                         \
            uint4 rr = make_uint4(pk2(u.x, u.y), pk2(u.z, u.w),             \
                                  pk2(v.x, v.y), pk2(v.z, v.w));            \
            AF[kk] = __builtin_bit_cast(bf16x8, rr);                        \
        }                                                                   \
    } while (0)
#define GATEC(AF, EOUT)                                                     \
    do {                                                                    \
        float eacc_ = 0.f;                                                  \
        _Pragma("unroll")                                                   \
        for (int hf = 0; hf < 8; ++hf) {                                    \
            f32x4 acc_ = (f32x4){0.f,0.f,0.f,0.f};                          \
            _Pragma("unroll")                                               \
            for (int kk = 0; kk < 4; ++kk) {                                \
                bf16x8 wuf_ = lds8(sW, 16 * hf + l15, kk * 64 + g4 * 16);   \
                acc_ = __builtin_amdgcn_mfma_f32_16x16x32_bf16(wuf_, AF[kk], acc_, 0, 0, 0); \
            }                                                               \
            f4 flp4_ = *(const f4*)&flp_s[sl][16 * hf + 4 * g4];            \
            f4 we4_  = *(const f4*)&we_s[16 * hf + 4 * g4];                 \
            _Pragma("unroll")                                               \
            for (int r = 0; r < 4; ++r) {                                   \
                float x_ = acc_[r] + flp4_[r];                              \
                eacc_ += we4_[r] * __frcp_rn(1.f + __expf(-x_));            \
            }                                                               \
        }                                                                   \
        eacc_ += __shfl_xor(eacc_, 16);                                     \
        eacc_ += __shfl_xor(eacc_, 32);                                     \
        EOUT = eacc_;                                                       \
    } while (0)

    for (int s = 0; s < 2; ++s) {
        int sl = 2 * w + s, seg = seg0 + sl;
        const float* fb = feat + (long)seg * NPS * D;
        f4 rawA[8], rawB[8];
        bf16x8 af[4];
        float e_c[4];
        LOADC(rawA, 0);
        LOADC(rawB, 1);                          // chunks 0,1 in flight
        PACKC(rawA, af);
        LOADC(rawA, 2);                          // chunk 2 under compute
        GATEC(af, e_c[0]);
        PACKC(rawB, af);
        LOADC(rawB, 3);                          // chunk 3 under compute
        GATEC(af, e_c[1]);
        PACKC(rawA, af);
        GATEC(af, e_c[2]);
        PACKC(rawB, af);
        GATEC(af, e_c[3]);
        if (g4 == 0) {
#pragma unroll
            for (int c = 0; c < 4; ++c) e_out[seg * 64 + 16 * c + l15] = e_c[c];
        }
    }
#undef LOADC
#undef PACKC
#undef GATEC
}

// ---------- K2c: softmax + weighted sums. Zero LDS, zero barriers, ~50 VGPR ----
// rst = scl*(sum alpha*raw) + shf ; pos = scl*(sum pw*raw) + shf*sum(pw).
__global__ __launch_bounds__(256)
void k_sw(const float* __restrict__ feat,
          const float* __restrict__ pw,
          const float* __restrict__ e_in,
          const float* __restrict__ scl,
          const float* __restrict__ shf,
          float* __restrict__ out) {
    int t = threadIdx.x, lane = t & 63, w = t >> 6;
    int seg0 = blockIdx.x * 8;
    for (int s = 0; s < 2; ++s) {
        int seg = seg0 + 2 * w + s;
        const float* fb = feat + (long)seg * NPS * D;
        float e = e_in[seg * 64 + lane];
        float m = e;
#pragma unroll
        for (int off = 32; off > 0; off >>= 1) m = fmaxf(m, __shfl_xor(m, off));
        float ex = __expf(e - m);
        float sd = ex;
#pragma unroll
        for (int off = 32; off > 0; off >>= 1) sd += __shfl_xor(sd, off);
        float al = ex / sd;                      // alpha for node == lane
        float pwv = pw[seg * 64 + lane];
        float spw = pwv;
#pragma unroll
        for (int off = 32; off > 0; off >>= 1) spw += __shfl_xor(spw, off);

        int q = lane >> 5, cc = lane & 31;
        f4 racc = {0.f,0.f,0.f,0.f}, pacc = {0.f,0.f,0.f,0.f};
#pragma unroll 8
        for (int k = 0; k < 32; ++k) {
            int n = q + 2 * k;
            f4 v = *(const f4*)(fb + n * 128 + cc * 4);
            float av = __shfl(al, n);
            float pv = __shfl(pwv, n);
            racc += av * v;
            pacc += pv * v;
        }
#pragma unroll
        for (int j = 0; j < 4; ++j) {
            racc[j] += __shfl_xor(racc[j], 32);
            pacc[j] += __shfl_xor(pacc[j], 32);
        }
        if (lane < 32) {
            f4 sc4 = *(const f4*)(scl + 4 * cc);
            f4 sh4 = *(const f4*)(shf + 4 * cc);
            *(f4*)(out + (long)seg * 128 + 4 * cc) = sc4 * racc + sh4;
            *(f4*)(out + (long)N_SEG * 128 + (long)seg * 128 + 4 * cc) =
                sc4 * pacc + sh4 * spw;
        }
    }
}

extern "C" void kernel_launch(void* const* d_in, const int* in_sizes, int n_in,
                              void* d_out, int out_size, void* d_ws, size_t ws_size,
                              hipStream_t stream) {
    const float* feat       = (const float*)d_in[0];
    const float* pw         = (const float*)d_in[1];
    // d_in[2] last_nodes: last node of seg s is 64s+63 (implicit)
    // d_in[3] segment_ids: contiguous equal segments (seg = node>>6) -- implicit
    const float* gamma      = (const float*)d_in[4];
    const float* beta       = (const float*)d_in[5];
    const float* Wu         = (const float*)d_in[6];
    const float* Wi         = (const float*)d_in[7];
    const float* bi         = (const float*)d_in[8];
    const float* we         = (const float*)d_in[9];
    float* out = (float*)d_out;

    float* ws   = (float*)d_ws;
    float* part = ws;                        // 524288 floats (2 MB)
    float* wscl = ws + 524288;               // 128
    float* wshf = ws + 524416;               // 128
    float* wcu  = ws + 524544;               // 128
    float* wflp = ws + 524672;               // 16384*128 floats (8 MB)
    float* we_b = ws + 2621824;              // 1048576 floats (4 MB)  [~14.7 MB total]

    k_stats<<<dim3(2048), dim3(256), 0, stream>>>(feat, part);
    k_scale<<<dim3(128),  dim3(256), 0, stream>>>(part, gamma, beta, wscl, wshf);
    k_const<<<dim3(1),    dim3(128), 0, stream>>>(Wu, wshf, wcu);
    k_flp  <<<dim3(512),  dim3(256), 0, stream>>>(feat, Wi, bi, wscl, wshf, wcu, wflp);
    k_e    <<<dim3(2048), dim3(256), 0, stream>>>(feat, Wu, we, wscl, wflp, we_b);
    k_sw   <<<dim3(2048), dim3(256), 0, stream>>>(feat, pw, we_b, wscl, wshf, out);
}

// Round 21
// 348.605 us; speedup vs baseline: 1.2250x; 1.2250x over previous
//
#include <hip/hip_runtime.h>

#define N_NODES 1048576
#define N_SEG   16384
#define NPS     64
#define D       128
#define EPS     1e-5f

typedef float f4 __attribute__((ext_vector_type(4)));
typedef float f32x4 __attribute__((ext_vector_type(4)));
typedef __bf16 bf16x8 __attribute__((ext_vector_type(8)));
typedef unsigned u32x4 __attribute__((ext_vector_type(4)));

// ---------- K1: column sum / sumsq partials (deterministic, no atomics) ----------
__global__ __launch_bounds__(256) void k_stats(const float* __restrict__ feat,
                                               float* __restrict__ part) {
    int t = threadIdx.x;
    long gid = (long)blockIdx.x * 256 + t;       // float4 index
    const f4* f4p = (const f4*)feat;
    f4 s = {0.f,0.f,0.f,0.f}, q = {0.f,0.f,0.f,0.f};
#pragma unroll 8
    for (int k = 0; k < 64; ++k) {
        f4 v = f4p[gid + (long)k * 524288];      // stride = 2048*256 float4s
        s += v;
        q += v * v;
    }
    __shared__ f4 red[2][8][32];
    red[0][t >> 5][t & 31] = s;
    red[1][t >> 5][t & 31] = q;
    __syncthreads();
    int stat = t >> 7, c = t & 127;
    const float* base = (const float*)&red[stat][0][0];
    float acc = 0.f;
#pragma unroll
    for (int r = 0; r < 8; ++r) acc += base[r * 128 + c];
    part[(stat * 128 + c) * 2048 + blockIdx.x] = acc;
}

// ---------- K1b: reduce partials -> scale/shift ----------
__global__ __launch_bounds__(256) void k_scale(const float* __restrict__ part,
                                               const float* __restrict__ gamma,
                                               const float* __restrict__ beta,
                                               float* __restrict__ scl,
                                               float* __restrict__ shf) {
    int t = threadIdx.x, c = blockIdx.x;
    float s1 = 0.f, s2 = 0.f;
#pragma unroll
    for (int j = 0; j < 8; ++j) {
        s1 += part[c * 2048 + t + 256 * j];
        s2 += part[(128 + c) * 2048 + t + 256 * j];
    }
    __shared__ float rs[256], rq[256];
    rs[t] = s1; rq[t] = s2;
    __syncthreads();
    for (int off = 128; off > 0; off >>= 1) {
        if (t < off) { rs[t] += rs[t + off]; rq[t] += rq[t + off]; }
        __syncthreads();
    }
    if (t == 0) {
        float mean = rs[0] / (float)N_NODES;
        float var  = rq[0] / (float)N_NODES - mean * mean;
        float sc   = gamma[c] * rsqrtf(var + EPS);
        scl[c] = sc;
        shf[c] = beta[c] - mean * sc;
    }
}

// ---------- helpers ----------
__device__ inline unsigned pk2(float x, float y) {   // pack 2 floats -> 2 bf16 (RNE)
    unsigned a = __builtin_bit_cast(unsigned, x);
    unsigned b = __builtin_bit_cast(unsigned, y);
    a = (a + 0x7fffu + ((a >> 16) & 1u)) >> 16;
    b = (b + 0x7fffu + ((b >> 16) & 1u)) & 0xffff0000u;
    return a | b;
}
__device__ inline bf16x8 lds8(const unsigned short* p, int row, int kb) {
    int addr = (row * 256 + kb) ^ ((row & 7) << 4);  // T2 XOR swizzle (bf16 tile)
    return *(const bf16x8*)((const char*)p + addr);
}
// load one B-fragment (col h, k-chunk kk/g4) straight from a global f32 [128][128] matrix
__device__ inline bf16x8 bfrag(const float* __restrict__ W, int h, int kk, int g4) {
    const float* p = W + h * 128 + kk * 32 + g4 * 8;
    f4 u = *(const f4*)p;
    f4 v = *(const f4*)(p + 4);
    u32x4 r = { pk2(u.x, u.y), pk2(u.z, u.w), pk2(v.x, v.y), pk2(v.z, v.w) };
    return __builtin_bit_cast(bf16x8, r);
}
// DRAIN-FREE barrier (m201 pattern): no "memory" clobber, so the compiler's
// waitcnt pass does NOT insert vmcnt(0) here — global prefetch loads stay in
// flight across it. lgkmcnt(0) makes LDS writes visible; sched_barrier(0)
// pins LDS ops on their side of the barrier.
__device__ inline void barx() {
    __builtin_amdgcn_sched_barrier(0);
    asm volatile("s_waitcnt lgkmcnt(0)");
    __builtin_amdgcn_s_barrier();
    __builtin_amdgcn_sched_barrier(0);
}

// ---------- K2: fused normalize + GEMM(bf16 MFMA) + gate + segment softmax + sums ----
// BEST-MEASURED CONFIG (R11/R19: 348.1us total). Block-lockstep, depth-1 register
// prefetch, drain-free barriers, waves_per_eu(2,2) pin. 20 structural variants
// mapped R2-R20; this is the measured optimum of the design space.
__global__ __launch_bounds__(256)
__attribute__((amdgpu_waves_per_eu(2, 2)))
void k_main(const float* __restrict__ feat,
            const float* __restrict__ pw,
            const float* __restrict__ Wu,
            const float* __restrict__ Wi,
            const float* __restrict__ bi,
            const float* __restrict__ we,
            const float* __restrict__ scl,
            const float* __restrict__ shf,
            float* __restrict__ out) {
    __shared__ __align__(16) unsigned short abuf[64 * 128];  // 16KB bf16 swizzled tile
    __shared__ float flp_s[8][128];                          // 4KB
    __shared__ float pw_s[512];                              // 2KB
    __shared__ float epart[4][64];                           // 1KB
    __shared__ float wpR[2][4][128];                         // 4KB double-buffered
    __shared__ float wpP[2][4][128];                         // 4KB

    int t = threadIdx.x;
    int lane = t & 63, w = t >> 6;
    int l15 = lane & 15, g4 = lane >> 4;
    int c0 = 4 * (t & 31);
    f4 vscl = *(const f4*)(scl + c0);
    f4 vshf = *(const f4*)(shf + c0);
    int h_a = l15 + 32 * w;
    int h_b = h_a + 16;
    int seg0 = blockIdx.x * 8;

    // ---- prologue: issue tile-0 and tile-1 loads FIRST (oldest in vmem queue) ----
    f4 fnA[8], fnB[8];
    {
        const f4* srcA = (const f4*)(feat + (long)seg0 * NPS * D);
#pragma unroll
        for (int k = 0; k < 8; ++k) fnA[k] = srcA[t + 256 * k];
        const f4* srcB = (const f4*)(feat + (long)(seg0 + 1) * NPS * D);
#pragma unroll
        for (int k = 0; k < 8; ++k) fnB[k] = srcB[t + 256 * k];
    }
    __builtin_amdgcn_sched_barrier(0);

    pw_s[t] = pw[seg0 * NPS + t];
    pw_s[t + 256] = pw[seg0 * NPS + t + 256];
    {   // last rows of the 8 segments -> abuf rows 0..7 (bf16), rows 8..15 zero
        int r = t >> 5;
        long row = (long)(seg0 + r) * NPS + (NPS - 1);
        f4 v = *(const f4*)(feat + row * 128 + c0);
        v = v * vscl + vshf;
        int addr = (r * 256 + 8 * (t & 31)) ^ ((r & 7) << 4);
        *(uint2*)((char*)abuf + addr) = make_uint2(pk2(v.x, v.y), pk2(v.z, v.w));
        int r2 = r + 8;
        int addr2 = (r2 * 256 + 8 * (t & 31)) ^ ((r2 & 7) << 4);
        *(uint2*)((char*)abuf + addr2) = make_uint2(0u, 0u);
    }
    barx();
    {   // flp[seg][h] = f_last @ Wi^T + bi  (one MFMA sweep over abuf rows 0..15)
        f32x4 a2[2];
        a2[0] = (f32x4){0.f,0.f,0.f,0.f};
        a2[1] = (f32x4){0.f,0.f,0.f,0.f};
#pragma unroll
        for (int kk = 0; kk < 4; ++kk) {
            bf16x8 a = lds8(abuf, l15, kk * 64 + g4 * 16);
            a2[0] = __builtin_amdgcn_mfma_f32_16x16x32_bf16(a, bfrag(Wi, h_a, kk, g4), a2[0], 0, 0, 0);
            a2[1] = __builtin_amdgcn_mfma_f32_16x16x32_bf16(a, bfrag(Wi, h_b, kk, g4), a2[1], 0, 0, 0);
        }
        float bia = bi[h_a], bib = bi[h_b];
#pragma unroll
        for (int r = 0; r < 4; ++r) {
            int si = 4 * g4 + r;
            if (si < 8) {
                flp_s[si][h_a] = a2[0][r] + bia;
                flp_s[si][h_b] = a2[1][r] + bib;
            }
        }
    }
    // loop-invariant Wu B-fragments (32 VGPRs)
    bf16x8 bW[8];
#pragma unroll
    for (int kk = 0; kk < 4; ++kk) {
        bW[kk]     = bfrag(Wu, h_a, kk, g4);
        bW[4 + kk] = bfrag(Wu, h_b, kk, g4);
    }
    float we0 = we[h_a], we1 = we[h_b];
    barx();   // flp_s/pw_s visible; abuf free for pack

// ---- one segment iteration. FN: static reg-buffer name. 2 barriers. ----
// bar_A: abuf(SL) ready + wp[(SL-1)&1] ready (deferred store source)
// bar_B: epart ready + all abuf reads done (abuf freed for next pack)
#define PROC_SEG(SL, FN, PSL, FIRST)                                                 \
    do {                                                                             \
        int seg = seg0 + (SL);                                                       \
        f4 v[8];                             /* f32 tile kept for weighted sums */   \
        _Pragma("unroll")                                                            \
        for (int k = 0; k < 8; ++k) {        /* pack: regs -> normalize -> abuf */   \
            v[k] = FN[k] * vscl + vshf;                                              \
            int n = (t >> 5) + 8 * k;                                                \
            int addr = (n * 256 + 8 * (t & 31)) ^ ((n & 7) << 4);                    \
            *(uint2*)((char*)abuf + addr) = make_uint2(pk2(v[k].x, v[k].y), pk2(v[k].z, v[k].w)); \
        }                                                                            \
        barx();                              /* bar_A */                             \
        if ((PSL) < 8) {                     /* refill FN with tile (PSL) */         \
            const f4* src = (const f4*)(feat + (long)(seg0 + (PSL)) * NPS * D);      \
            _Pragma("unroll")                                                        \
            for (int k = 0; k < 8; ++k) FN[k] = src[t + 256 * k];                    \
        }                                                                            \
        __builtin_amdgcn_sched_barrier(0);   /* pin the load issue here */           \
        if (!(FIRST)) {                      /* deferred store of segment SL-1 */    \
            int ps = seg - 1, pb = (SL + 1) & 1;                                     \
            if (t < 128) {                                                           \
                out[(long)ps * 128 + t] =                                            \
                    wpR[pb][0][t] + wpR[pb][1][t] + wpR[pb][2][t] + wpR[pb][3][t];   \
            } else {                                                                 \
                int c = t - 128;                                                     \
                out[(long)N_SEG * 128 + (long)ps * 128 + c] =                        \
                    wpP[pb][0][c] + wpP[pb][1][c] + wpP[pb][2][c] + wpP[pb][3][c];   \
            }                                                                        \
        }                                                                            \
        float fl0 = flp_s[(SL)][h_a];                                                \
        float fl1 = flp_s[(SL)][h_b];                                                \
        f32x4 acc[4][2];                                                             \
        _Pragma("unroll")                                                            \
        for (int nf = 0; nf < 4; ++nf) {                                             \
            acc[nf][0] = (f32x4){0.f,0.f,0.f,0.f};                                   \
            acc[nf][1] = (f32x4){0.f,0.f,0.f,0.f};                                   \
        }                                                                            \
        _Pragma("unroll")                                                            \
        for (int kk = 0; kk < 4; ++kk) {                                             \
            int kb = kk * 64 + g4 * 16;                                              \
            bf16x8 a[4];                                                             \
            _Pragma("unroll")                                                        \
            for (int nf = 0; nf < 4; ++nf) a[nf] = lds8(abuf, l15 + 16 * nf, kb);    \
            _Pragma("unroll")                                                        \
            for (int nf = 0; nf < 4; ++nf) {                                         \
                acc[nf][0] = __builtin_amdgcn_mfma_f32_16x16x32_bf16(a[nf], bW[kk],     acc[nf][0], 0, 0, 0); \
                acc[nf][1] = __builtin_amdgcn_mfma_f32_16x16x32_bf16(a[nf], bW[4 + kk], acc[nf][1], 0, 0, 0); \
            }                                                                        \
        }                                                                            \
        _Pragma("unroll")                                                            \
        for (int nf = 0; nf < 4; ++nf) {                                             \
            _Pragma("unroll")                                                        \
            for (int r = 0; r < 4; ++r) {                                            \
                float x0 = acc[nf][0][r] + fl0;                                      \
                float x1 = acc[nf][1][r] + fl1;                                      \
                float p = we0 / (1.f + __expf(-x0)) + we1 / (1.f + __expf(-x1));     \
                p += __shfl_xor(p, 1);                                               \
                p += __shfl_xor(p, 2);                                               \
                p += __shfl_xor(p, 4);                                               \
                p += __shfl_xor(p, 8);                                               \
                if (l15 == 0) epart[w][16 * nf + 4 * g4 + r] = p;                    \
            }                                                                        \
        }                                                                            \
        barx();                              /* bar_B */                             \
        float e = epart[0][lane] + epart[1][lane] + epart[2][lane] + epart[3][lane]; \
        float m = e;                                                                 \
        _Pragma("unroll")                                                            \
        for (int off = 32; off > 0; off >>= 1) m = fmaxf(m, __shfl_xor(m, off));     \
        float ex = __expf(e - m);                                                    \
        float sd = ex;                                                               \
        _Pragma("unroll")                                                            \
        for (int off = 32; off > 0; off >>= 1) sd += __shfl_xor(sd, off);            \
        float al = ex / sd;                                                          \
        f4 racc = {0.f,0.f,0.f,0.f}, pacc = {0.f,0.f,0.f,0.f};                       \
        _Pragma("unroll")                                                            \
        for (int k = 0; k < 8; ++k) {        /* ws from f32 v regs (no abuf read) */ \
            int n = (t >> 5) + 8 * k;                                                \
            float av = __shfl(al, n);                                                \
            float pv = pw_s[(SL) * NPS + n];                                         \
            racc += av * v[k];                                                       \
            pacc += pv * v[k];                                                       \
        }                                                                            \
        _Pragma("unroll")                                                            \
        for (int c = 0; c < 4; ++c) {                                                \
            racc[c] += __shfl_xor(racc[c], 32);                                      \
            pacc[c] += __shfl_xor(pacc[c], 32);                                      \
        }                                                                            \
        if (lane < 32) {                                                             \
            *(f4*)&wpR[(SL) & 1][w][4 * lane] = racc;                                \
            *(f4*)&wpP[(SL) & 1][w][4 * lane] = pacc;                                \
        }                                                                            \
    } while (0)

    for (int it = 0; it < 8; it += 2) {
        PROC_SEG(it,     fnA, it + 2, it == 0);
        PROC_SEG(it + 1, fnB, it + 3, false);
    }
#undef PROC_SEG

    // epilogue: store segment seg0+7 from wp[1]
    barx();
    if (t < 128) {
        out[(long)(seg0 + 7) * 128 + t] =
            wpR[1][0][t] + wpR[1][1][t] + wpR[1][2][t] + wpR[1][3][t];
    } else {
        int c = t - 128;
        out[(long)N_SEG * 128 + (long)(seg0 + 7) * 128 + c] =
            wpP[1][0][c] + wpP[1][1][c] + wpP[1][2][c] + wpP[1][3][c];
    }
}

extern "C" void kernel_launch(void* const* d_in, const int* in_sizes, int n_in,
                              void* d_out, int out_size, void* d_ws, size_t ws_size,
                              hipStream_t stream) {
    const float* feat       = (const float*)d_in[0];
    const float* pw         = (const float*)d_in[1];
    // d_in[2] last_nodes: last node of seg s is 64s+63 (implicit)
    // d_in[3] segment_ids: contiguous equal segments (seg = node>>6) -- implicit
    const float* gamma      = (const float*)d_in[4];
    const float* beta       = (const float*)d_in[5];
    const float* Wu         = (const float*)d_in[6];
    const float* Wi         = (const float*)d_in[7];
    const float* bi         = (const float*)d_in[8];
    const float* we         = (const float*)d_in[9];
    float* out = (float*)d_out;

    float* ws   = (float*)d_ws;
    float* part = ws;                       // 256*2048 floats (2 MB)
    float* wscl = ws + 524288;              // 128
    float* wshf = ws + 524288 + 128;        // 128

    k_stats<<<dim3(2048), dim3(256), 0, stream>>>(feat, part);
    k_scale<<<dim3(128),  dim3(256), 0, stream>>>(part, gamma, beta, wscl, wshf);
    k_main <<<dim3(2048), dim3(256), 0, stream>>>(feat, pw, Wu, Wi, bi, we, wscl, wshf, out);
}